// Round 10
// baseline (169.645 us; speedup 1.0000x reference)
//
#include <hip/hip_runtime.h>
#include <hip/hip_bf16.h>
#include <cstdint>
#include <cstddef>

// Problem constants: T=1024, H=1024, I=512, E=16, K=4
#define T_TOK 1024
#define HDIM  1024
#define IDIM  512
#define NEXP  16
#define TOPK  4
#define CAP   1024   // per-expert entry capacity

typedef __bf16 bf16;
typedef __attribute__((ext_vector_type(8))) __bf16 bf16x8;
typedef __attribute__((ext_vector_type(4))) __bf16 bf16x4;
typedef __attribute__((ext_vector_type(4))) float f32x4;

#define BAR() __builtin_amdgcn_s_barrier()
#define SB()  __builtin_amdgcn_sched_barrier(0)
#define LGKM0() asm volatile("s_waitcnt lgkmcnt(0)" ::: "memory")
// counted waits: steady-state outstanding at step top = [B(k)4, A(k)4, B(k+1)4];
// vmcnt(4) retires B(k)+A(k), leaves B(k+1) in flight across both barriers.
#define WAIT_VM4 asm volatile("s_waitcnt vmcnt(4)" ::: "memory")
#define WAIT_VM0 asm volatile("s_waitcnt vmcnt(0)" ::: "memory")

__device__ __forceinline__ void lds_load16(void* lds_dst, const void* g_src) {
  __builtin_amdgcn_global_load_lds(
      (__attribute__((address_space(1))) unsigned int*)(void*)(g_src),
      (__attribute__((address_space(3))) unsigned int*)(lds_dst),
      16, 0, 0);
}

__device__ __forceinline__ bf16x4 cvt4(float4 a) {
  bf16x4 o;
  o[0] = (bf16)a.x; o[1] = (bf16)a.y; o[2] = (bf16)a.z; o[3] = (bf16)a.w;
  return o;
}

// ---------------- fused prep: cvt hid->bf16 (+zero row T) and routing ----------------

#define CVT_BLOCKS (T_TOK * HDIM / 4 / 256)   // 1024

__global__ void prep_kernel(const float* __restrict__ hid_f, bf16* __restrict__ hid_b,
                            const int* __restrict__ idx, const float* __restrict__ w,
                            int* __restrict__ etk, float* __restrict__ ew,
                            int* __restrict__ cntpad) {
  __shared__ int cnt;
  const int b = blockIdx.x;
  const int tid = threadIdx.x;
  if (b < CVT_BLOCKS) {
    int i = b * 256 + tid;
    float4 v = ((const float4*)hid_f)[i];
    ((bf16x4*)hid_b)[i] = cvt4(v);
    if (b == 0)  // zero pad row T
      ((bf16x4*)(hid_b + (size_t)T_TOK * HDIM))[tid] = cvt4(make_float4(0.f, 0.f, 0.f, 0.f));
    return;
  }
  const int e = b - CVT_BLOCKS;
  if (tid == 0) cnt = 0;
  __syncthreads();
  for (int j = tid; j < T_TOK * TOPK; j += blockDim.x) {
    if (idx[j] == e) {
      int slot = atomicAdd(&cnt, 1);
      if (slot < CAP) { etk[e * CAP + slot] = j; ew[e * CAP + slot] = w[j]; }
    }
  }
  __syncthreads();
  int c = cnt < CAP ? cnt : CAP;
  int p = (c + 127) & ~127;            // pad to M-tile (128)
  for (int j = c + tid; j < p; j += blockDim.x) {
    etk[e * CAP + j] = (T_TOK << 2);   // points at zeroed row T; kslot 0 -> slab pad row T
    ew[e * CAP + j] = 0.f;
  }
  if (tid == 0) cntpad[e] = p;
}

// ---------------- GEMM1: hsc[entry, i] = silu(g)*u*wgt ----------------
// v10 = v9 (R9-passing) skeleton + DEPTH-2 B prefetch with counted vmcnt.
// Step k: vmcnt(4) [retire B(k)+A(k), keep B(k+1) flying] -> ds_write B(k)
// -> lgkmcnt(0) -> s_barrier -> issue A(k+1) [L2 stream, depth-1] ->
// load B(k+2) into the just-consumed reg set [HBM stream, depth-2] -> MFMA.
// Prologue establishes the invariant: issue B(0), A(0), B(1) in that order.
// Last step waits vmcnt(0). LDS 48 KB (3 blocks/CU), VGPR ~= v9.
// Tile M=128 x 32 i-ch (G+U), BK=64, 16 steps, waves 2m x 2i, 16 MFMA/wave/step.

__global__ __launch_bounds__(256, 3) void gemm1_kernel(
    const bf16* __restrict__ hid,    // [(T+1),H] bf16, row T zeroed
    const float* __restrict__ gup,   // [E,2I,H] fp32
    const int* __restrict__ etk, const float* __restrict__ ew,
    const int* __restrict__ cntpad,
    bf16* __restrict__ hsc) {        // [E*CAP, I] bf16
  __shared__ __align__(16) bf16 As[2][128 * 64];  // 32 KB
  __shared__ __align__(16) bf16 Bs[2][64 * 64];   // 16 KB (32 G rows + 32 U rows)
  const int e = blockIdx.y, z = blockIdx.z;
  const int ntiles = cntpad[e] >> 7;
  const int n0 = blockIdx.x * 32;
  const int ebase = e * CAP;
  const int tid = threadIdx.x, lane = tid & 63, wid = tid >> 6;
  const int wm = (wid >> 1) * 64, wi = (wid & 1) * 16;
  const int lcol = lane & 15, lquad = lane >> 4;
  const int l7 = lcol & 7;
  const int srow = tid >> 3;
  const int swz = ((tid & 7) ^ (srow & 7)) * 8;
  const int r = tid >> 2;
  const int c0 = (tid & 3) * 4;
  const int grow = (r < 32) ? (n0 + r) : (IDIM + n0 + (r - 32));
  const float* gB = gup + (size_t)e * (2 * IDIM) * HDIM + (size_t)grow * HDIM + c0;
  int wb[4];
#pragma unroll
  for (int j = 0; j < 4; ++j) {
    int c = c0 + 16 * j;
    wb[j] = (((c >> 3) ^ (r & 7)) * 8) + (c & 7);
  }
  const int bst = r * 64;

  for (int mt = z; mt < ntiles; mt += 3) {
    const int mrow = ebase + mt * 128;
    const bf16* gA[4];
#pragma unroll
    for (int q = 0; q < 4; ++q)
      gA[q] = hid + (size_t)(etk[mrow + srow + 32 * q] >> 2) * HDIM + swz;
    f32x4 aG[4], aU[4];
#pragma unroll
    for (int mf = 0; mf < 4; ++mf) {
      aG[mf] = f32x4{0.f, 0.f, 0.f, 0.f};
      aU[mf] = f32x4{0.f, 0.f, 0.f, 0.f};
    }
    float4 bvA[4], bvB[4];

    // prologue: establish S(0) = [B(0), A(0), B(1)] (12 outstanding, in order)
#pragma unroll
    for (int j = 0; j < 4; ++j) bvA[j] = *(const float4*)(gB + 16 * j);      // B(0)
    SB();
#pragma unroll
    for (int q = 0; q < 4; ++q)
      lds_load16(&As[0][tid * 8 + q * 2048], gA[q]);                          // A(0)
    SB();
#pragma unroll
    for (int j = 0; j < 4; ++j) bvB[j] = *(const float4*)(gB + 64 + 16 * j); // B(1)
    SB();

    // STEP k: bcur holds B(k) (set k&1); B(k+2) reloads into bcur after consume
    auto STEP = [&](int k, int cur, float4 (&bcur)[4]) {
      const int nxt = cur ^ 1;
      if (k == 15) { WAIT_VM0; } else { WAIT_VM4; }   // B(k)+A(k) retired
      SB();
#pragma unroll
      for (int j = 0; j < 4; ++j)
        *(bf16x4*)&Bs[cur][bst + wb[j]] = cvt4(bcur[j]);
      LGKM0();   // DS visibility only; B(k+1) [and later issues] stay in flight
      SB();
      BAR();
      SB();
      if (k + 1 < 16) {   // A(k+1): L2-resident stream, depth-1 suffices
#pragma unroll
        for (int q = 0; q < 4; ++q)
          lds_load16(&As[nxt][tid * 8 + q * 2048], gA[q] + (k + 1) * 64);
      }
      SB();
      if (k + 2 < 16) {   // B(k+2): HBM stream, depth-2, into just-freed set
#pragma unroll
        for (int j = 0; j < 4; ++j)
          bcur[j] = *(const float4*)(gB + (k + 2) * 64 + 16 * j);
      }
      SB();
#pragma unroll
      for (int ks = 0; ks < 2; ++ks) {
        const int sw = ((ks * 4 + lquad) ^ l7) * 8;
        bf16x8 bg = *(const bf16x8*)&Bs[cur][(wi + lcol) * 64 + sw];
        bf16x8 bu = *(const bf16x8*)&Bs[cur][(32 + wi + lcol) * 64 + sw];
#pragma unroll
        for (int mf = 0; mf < 4; ++mf) {
          bf16x8 af = *(const bf16x8*)&As[cur][(wm + mf * 16 + lcol) * 64 + sw];
          aG[mf] = __builtin_amdgcn_mfma_f32_16x16x32_bf16(af, bg, aG[mf], 0, 0, 0);
          aU[mf] = __builtin_amdgcn_mfma_f32_16x16x32_bf16(af, bu, aU[mf], 0, 0, 0);
        }
      }
    };
#pragma unroll
    for (int kk = 0; kk < 8; ++kk) {
      STEP(2 * kk,     0, bvA);
      STEP(2 * kk + 1, 1, bvB);
    }
    // epilogue: C/D col=lane&15, row=lquad*4+rr
#pragma unroll
    for (int mf = 0; mf < 4; ++mf) {
#pragma unroll
      for (int rr = 0; rr < 4; ++rr) {
        const int erow = mt * 128 + wm + mf * 16 + lquad * 4 + rr;
        const float wgt = ew[ebase + erow];
        float g = aG[mf][rr], u = aU[mf][rr];
        float s = g / (1.f + __expf(-g));
        hsc[(size_t)(ebase + erow) * IDIM + n0 + wi + lcol] = (bf16)(s * u * wgt);
      }
    }
  }
}

// ---------------- GEMM2: slab[k][tok,h] = hsc[entry,:] . down[e,h,:] ----------------
// Same v10 discipline, 8 K-steps. Tile M=128 x 64 h-ch, waves 2m x 2h,
// 16 MFMA/wave/step. Slabs + reduce epilogue.

__global__ __launch_bounds__(256, 3) void gemm2_kernel(
    const bf16* __restrict__ hsc,    // [E*CAP, I] bf16
    const float* __restrict__ down,  // [E,H,I] fp32
    const int* __restrict__ etk, const int* __restrict__ cntpad,
    float* __restrict__ slabs) {     // [4][(T+1)][H] fp32
  __shared__ __align__(16) bf16 As[2][128 * 64];  // 32 KB
  __shared__ __align__(16) bf16 Bs[2][64 * 64];   // 16 KB
  const int e = blockIdx.y, z = blockIdx.z;
  const int ntiles = cntpad[e] >> 7;
  const int n0 = blockIdx.x * 64;
  const int ebase = e * CAP;
  const int tid = threadIdx.x, lane = tid & 63, wid = tid >> 6;
  const int wm = (wid >> 1) * 64, wh = (wid & 1) * 32;
  const int lcol = lane & 15, lquad = lane >> 4;
  const int l7 = lcol & 7;
  const int srow = tid >> 3;
  const int swz = ((tid & 7) ^ (srow & 7)) * 8;
  const int r = tid >> 2;
  const int c0 = (tid & 3) * 4;
  const float* gB = down + (size_t)e * HDIM * IDIM + (size_t)(n0 + r) * IDIM + c0;
  int wb[4];
#pragma unroll
  for (int j = 0; j < 4; ++j) {
    int c = c0 + 16 * j;
    wb[j] = (((c >> 3) ^ (r & 7)) * 8) + (c & 7);
  }
  const int bst = r * 64;

  for (int mt = z; mt < ntiles; mt += 3) {
    const size_t rbase = (size_t)(ebase + mt * 128);
    const bf16* gA[4];
#pragma unroll
    for (int q = 0; q < 4; ++q)
      gA[q] = hsc + (rbase + srow + 32 * q) * IDIM + swz;
    f32x4 acc[4][2];
#pragma unroll
    for (int mf = 0; mf < 4; ++mf) {
      acc[mf][0] = f32x4{0.f, 0.f, 0.f, 0.f};
      acc[mf][1] = f32x4{0.f, 0.f, 0.f, 0.f};
    }
    float4 bvA[4], bvB[4];
    // prologue: B(0), A(0), B(1)
#pragma unroll
    for (int j = 0; j < 4; ++j) bvA[j] = *(const float4*)(gB + 16 * j);
    SB();
#pragma unroll
    for (int q = 0; q < 4; ++q)
      lds_load16(&As[0][tid * 8 + q * 2048], gA[q]);
    SB();
#pragma unroll
    for (int j = 0; j < 4; ++j) bvB[j] = *(const float4*)(gB + 64 + 16 * j);
    SB();

    auto STEP = [&](int k, int cur, float4 (&bcur)[4]) {
      const int nxt = cur ^ 1;
      if (k == 7) { WAIT_VM0; } else { WAIT_VM4; }
      SB();
#pragma unroll
      for (int j = 0; j < 4; ++j)
        *(bf16x4*)&Bs[cur][bst + wb[j]] = cvt4(bcur[j]);
      LGKM0();
      SB();
      BAR();
      SB();
      if (k + 1 < 8) {
#pragma unroll
        for (int q = 0; q < 4; ++q)
          lds_load16(&As[nxt][tid * 8 + q * 2048], gA[q] + (k + 1) * 64);
      }
      SB();
      if (k + 2 < 8) {
#pragma unroll
        for (int j = 0; j < 4; ++j)
          bcur[j] = *(const float4*)(gB + (k + 2) * 64 + 16 * j);
      }
      SB();
#pragma unroll
      for (int ks = 0; ks < 2; ++ks) {
        const int sw = ((ks * 4 + lquad) ^ l7) * 8;
        bf16x8 b0 = *(const bf16x8*)&Bs[cur][(wh + lcol) * 64 + sw];
        bf16x8 b1 = *(const bf16x8*)&Bs[cur][(wh + 16 + lcol) * 64 + sw];
#pragma unroll
        for (int mf = 0; mf < 4; ++mf) {
          bf16x8 af = *(const bf16x8*)&As[cur][(wm + mf * 16 + lcol) * 64 + sw];
          acc[mf][0] = __builtin_amdgcn_mfma_f32_16x16x32_bf16(af, b0, acc[mf][0], 0, 0, 0);
          acc[mf][1] = __builtin_amdgcn_mfma_f32_16x16x32_bf16(af, b1, acc[mf][1], 0, 0, 0);
        }
      }
    };
#pragma unroll
    for (int kk = 0; kk < 4; ++kk) {   // IDIM/64 = 8 steps
      STEP(2 * kk,     0, bvA);
      STEP(2 * kk + 1, 1, bvB);
    }
    // epilogue: plain scatter stores (each (t,k) slab row written once per n-slice)
#pragma unroll
    for (int mf = 0; mf < 4; ++mf) {
#pragma unroll
      for (int rr = 0; rr < 4; ++rr) {
        const int tk = etk[ebase + mt * 128 + wm + mf * 16 + lquad * 4 + rr];
        const int tok = tk >> 2, kslot = tk & 3;
        float* orow = slabs + ((size_t)kslot * (T_TOK + 1) + tok) * HDIM + n0 + wh + lcol;
        orow[0] = acc[mf][0][rr];
        orow[16] = acc[mf][1][rr];
      }
    }
  }
}

// ---------------- reduce: out = sum of 4 slabs ----------------

__global__ void reduce_kernel(const float* __restrict__ slabs, float* __restrict__ out) {
  const size_t stride = (size_t)(T_TOK + 1) * HDIM;
  int i = blockIdx.x * blockDim.x + threadIdx.x;
  float4 a = ((const float4*)slabs)[i];
  float4 b = ((const float4*)(slabs + stride))[i];
  float4 c = ((const float4*)(slabs + 2 * stride))[i];
  float4 d = ((const float4*)(slabs + 3 * stride))[i];
  float4 o;
  o.x = a.x + b.x + c.x + d.x;
  o.y = a.y + b.y + c.y + d.y;
  o.z = a.z + b.z + c.z + d.z;
  o.w = a.w + b.w + c.w + d.w;
  ((float4*)out)[i] = o;
}

// ---------------- launch ----------------

extern "C" void kernel_launch(void* const* d_in, const int* in_sizes, int n_in,
                              void* d_out, int out_size, void* d_ws, size_t ws_size,
                              hipStream_t stream) {
  const float* hid_f  = (const float*)d_in[0];
  const int*   idx    = (const int*)d_in[1];
  const float* tw     = (const float*)d_in[2];
  const float* gup_f  = (const float*)d_in[3];
  const float* down_f = (const float*)d_in[4];
  float* out = (float*)d_out;

  uint8_t* ws = (uint8_t*)d_ws;
  size_t off = 0;
  bf16* hid_b = (bf16*)(ws + off);   off += (size_t)(T_TOK + 1) * HDIM * 2;
  int*  etk   = (int*)(ws + off);    off += (size_t)NEXP * CAP * 4;
  float* ewt  = (float*)(ws + off);  off += (size_t)NEXP * CAP * 4;
  int* cntpad = (int*)(ws + off);    off += 256;
  bf16* hsc   = (bf16*)(ws + off);   off += (size_t)NEXP * CAP * IDIM * 2;
  float* slabs = (float*)(ws + off); // 4*(T+1)*H*4 ≈ 16.8 MB

  prep_kernel<<<dim3(CVT_BLOCKS + NEXP), dim3(256), 0, stream>>>(
      hid_f, hid_b, idx, tw, etk, ewt, cntpad);
  gemm1_kernel<<<dim3(IDIM / 32, NEXP, 3), dim3(256), 0, stream>>>(
      hid_b, gup_f, etk, ewt, cntpad, hsc);
  gemm2_kernel<<<dim3(HDIM / 64, NEXP, 3), dim3(256), 0, stream>>>(
      hsc, down_f, etk, cntpad, slabs);
  reduce_kernel<<<dim3(T_TOK * HDIM / 4 / 256), dim3(256), 0, stream>>>(slabs, out);
}

// Round 11
// 168.377 us; speedup vs baseline: 1.0075x; 1.0075x over previous
//
#include <hip/hip_runtime.h>
#include <hip/hip_bf16.h>
#include <cstdint>
#include <cstddef>

// Problem constants: T=1024, H=1024, I=512, E=16, K=4
#define T_TOK 1024
#define HDIM  1024
#define IDIM  512
#define NEXP  16
#define TOPK  4
#define CAP   1024   // per-expert entry capacity

typedef __bf16 bf16;
typedef __attribute__((ext_vector_type(8))) __bf16 bf16x8;
typedef __attribute__((ext_vector_type(4))) __bf16 bf16x4;
typedef __attribute__((ext_vector_type(4))) float f32x4;

#define BAR() __builtin_amdgcn_s_barrier()
#define SB()  __builtin_amdgcn_sched_barrier(0)
#define LGKM0() asm volatile("s_waitcnt lgkmcnt(0)" ::: "memory")
// counted waits: steady-state outstanding at step top = [B(k)4, A(k)4, B(k+1)4];
// vmcnt(4) retires B(k)+A(k), leaves B(k+1) in flight across both barriers.
#define WAIT_VM4 asm volatile("s_waitcnt vmcnt(4)" ::: "memory")
#define WAIT_VM0 asm volatile("s_waitcnt vmcnt(0)" ::: "memory")

__device__ __forceinline__ void lds_load16(void* lds_dst, const void* g_src) {
  __builtin_amdgcn_global_load_lds(
      (__attribute__((address_space(1))) unsigned int*)(void*)(g_src),
      (__attribute__((address_space(3))) unsigned int*)(lds_dst),
      16, 0, 0);
}

__device__ __forceinline__ bf16x4 cvt4(float4 a) {
  bf16x4 o;
  o[0] = (bf16)a.x; o[1] = (bf16)a.y; o[2] = (bf16)a.z; o[3] = (bf16)a.w;
  return o;
}

// ---------------- fused prep: cvt hid->bf16 (+zero row T) and routing ----------------

#define CVT_BLOCKS (T_TOK * HDIM / 4 / 256)   // 1024

__global__ void prep_kernel(const float* __restrict__ hid_f, bf16* __restrict__ hid_b,
                            const int* __restrict__ idx, const float* __restrict__ w,
                            int* __restrict__ etk, float* __restrict__ ew,
                            int* __restrict__ cntpad) {
  __shared__ int cnt;
  const int b = blockIdx.x;
  const int tid = threadIdx.x;
  if (b < CVT_BLOCKS) {
    int i = b * 256 + tid;
    float4 v = ((const float4*)hid_f)[i];
    ((bf16x4*)hid_b)[i] = cvt4(v);
    if (b == 0)  // zero pad row T
      ((bf16x4*)(hid_b + (size_t)T_TOK * HDIM))[tid] = cvt4(make_float4(0.f, 0.f, 0.f, 0.f));
    return;
  }
  const int e = b - CVT_BLOCKS;
  if (tid == 0) cnt = 0;
  __syncthreads();
  for (int j = tid; j < T_TOK * TOPK; j += blockDim.x) {
    if (idx[j] == e) {
      int slot = atomicAdd(&cnt, 1);
      if (slot < CAP) { etk[e * CAP + slot] = j; ew[e * CAP + slot] = w[j]; }
    }
  }
  __syncthreads();
  int c = cnt < CAP ? cnt : CAP;
  int p = (c + 127) & ~127;            // pad to M-tile (128)
  for (int j = c + tid; j < p; j += blockDim.x) {
    etk[e * CAP + j] = (T_TOK << 2);   // points at zeroed row T; kslot 0 -> slab pad row T
    ew[e * CAP + j] = 0.f;
  }
  if (tid == 0) cntpad[e] = p;
}

// ---------------- GEMM1: hsc[entry, i] = silu(g)*u*wgt ----------------
// v10 body (R10-passing), unchanged: depth-2 B prefetch, counted vmcnt,
// no-drain raw barriers. Tile M=128 x 32 i-ch (G+U), BK=64, 16 steps,
// waves 2m x 2i, 16 MFMA/wave/step. LDS 48 KB (3 blocks/CU).

__global__ __launch_bounds__(256, 3) void gemm1_kernel(
    const bf16* __restrict__ hid,    // [(T+1),H] bf16, row T zeroed
    const float* __restrict__ gup,   // [E,2I,H] fp32
    const int* __restrict__ etk, const float* __restrict__ ew,
    const int* __restrict__ cntpad,
    bf16* __restrict__ hsc) {        // [E*CAP, I] bf16
  __shared__ __align__(16) bf16 As[2][128 * 64];  // 32 KB
  __shared__ __align__(16) bf16 Bs[2][64 * 64];   // 16 KB (32 G rows + 32 U rows)
  const int e = blockIdx.y, z = blockIdx.z;
  const int ntiles = cntpad[e] >> 7;
  const int n0 = blockIdx.x * 32;
  const int ebase = e * CAP;
  const int tid = threadIdx.x, lane = tid & 63, wid = tid >> 6;
  const int wm = (wid >> 1) * 64, wi = (wid & 1) * 16;
  const int lcol = lane & 15, lquad = lane >> 4;
  const int l7 = lcol & 7;
  const int srow = tid >> 3;
  const int swz = ((tid & 7) ^ (srow & 7)) * 8;
  const int r = tid >> 2;
  const int c0 = (tid & 3) * 4;
  const int grow = (r < 32) ? (n0 + r) : (IDIM + n0 + (r - 32));
  const float* gB = gup + (size_t)e * (2 * IDIM) * HDIM + (size_t)grow * HDIM + c0;
  int wb[4];
#pragma unroll
  for (int j = 0; j < 4; ++j) {
    int c = c0 + 16 * j;
    wb[j] = (((c >> 3) ^ (r & 7)) * 8) + (c & 7);
  }
  const int bst = r * 64;

  for (int mt = z; mt < ntiles; mt += 3) {
    const int mrow = ebase + mt * 128;
    const bf16* gA[4];
#pragma unroll
    for (int q = 0; q < 4; ++q)
      gA[q] = hid + (size_t)(etk[mrow + srow + 32 * q] >> 2) * HDIM + swz;
    f32x4 aG[4], aU[4];
#pragma unroll
    for (int mf = 0; mf < 4; ++mf) {
      aG[mf] = f32x4{0.f, 0.f, 0.f, 0.f};
      aU[mf] = f32x4{0.f, 0.f, 0.f, 0.f};
    }
    float4 bvA[4], bvB[4];

    // prologue: establish S(0) = [B(0), A(0), B(1)] (12 outstanding, in order)
#pragma unroll
    for (int j = 0; j < 4; ++j) bvA[j] = *(const float4*)(gB + 16 * j);      // B(0)
    SB();
#pragma unroll
    for (int q = 0; q < 4; ++q)
      lds_load16(&As[0][tid * 8 + q * 2048], gA[q]);                          // A(0)
    SB();
#pragma unroll
    for (int j = 0; j < 4; ++j) bvB[j] = *(const float4*)(gB + 64 + 16 * j); // B(1)
    SB();

    auto STEP = [&](int k, int cur, float4 (&bcur)[4]) {
      const int nxt = cur ^ 1;
      if (k == 15) { WAIT_VM0; } else { WAIT_VM4; }   // B(k)+A(k) retired
      SB();
#pragma unroll
      for (int j = 0; j < 4; ++j)
        *(bf16x4*)&Bs[cur][bst + wb[j]] = cvt4(bcur[j]);
      LGKM0();   // DS visibility only; B(k+1) stays in flight
      SB();
      BAR();
      SB();
      if (k + 1 < 16) {   // A(k+1): L2-resident stream, depth-1 suffices
#pragma unroll
        for (int q = 0; q < 4; ++q)
          lds_load16(&As[nxt][tid * 8 + q * 2048], gA[q] + (k + 1) * 64);
      }
      SB();
      if (k + 2 < 16) {   // B(k+2): HBM stream, depth-2, into just-freed set
#pragma unroll
        for (int j = 0; j < 4; ++j)
          bcur[j] = *(const float4*)(gB + (k + 2) * 64 + 16 * j);
      }
      SB();
#pragma unroll
      for (int ks = 0; ks < 2; ++ks) {
        const int sw = ((ks * 4 + lquad) ^ l7) * 8;
        bf16x8 bg = *(const bf16x8*)&Bs[cur][(wi + lcol) * 64 + sw];
        bf16x8 bu = *(const bf16x8*)&Bs[cur][(32 + wi + lcol) * 64 + sw];
#pragma unroll
        for (int mf = 0; mf < 4; ++mf) {
          bf16x8 af = *(const bf16x8*)&As[cur][(wm + mf * 16 + lcol) * 64 + sw];
          aG[mf] = __builtin_amdgcn_mfma_f32_16x16x32_bf16(af, bg, aG[mf], 0, 0, 0);
          aU[mf] = __builtin_amdgcn_mfma_f32_16x16x32_bf16(af, bu, aU[mf], 0, 0, 0);
        }
      }
    };
#pragma unroll
    for (int kk = 0; kk < 8; ++kk) {
      STEP(2 * kk,     0, bvA);
      STEP(2 * kk + 1, 1, bvB);
    }
    // epilogue: C/D col=lane&15, row=lquad*4+rr
#pragma unroll
    for (int mf = 0; mf < 4; ++mf) {
#pragma unroll
      for (int rr = 0; rr < 4; ++rr) {
        const int erow = mt * 128 + wm + mf * 16 + lquad * 4 + rr;
        const float wgt = ew[ebase + erow];
        float g = aG[mf][rr], u = aU[mf][rr];
        float s = g / (1.f + __expf(-g));
        hsc[(size_t)(ebase + erow) * IDIM + n0 + wi + lcol] = (bf16)(s * u * wgt);
      }
    }
  }
}

// ---------------- GEMM2: slab[k][tok,h] = hsc[entry,:] . down[e,h,:] ----------------
// v11: same v10 body; slabs now BF16 (halves scatter-store + reduce traffic).

__global__ __launch_bounds__(256, 3) void gemm2_kernel(
    const bf16* __restrict__ hsc,    // [E*CAP, I] bf16
    const float* __restrict__ down,  // [E,H,I] fp32
    const int* __restrict__ etk, const int* __restrict__ cntpad,
    bf16* __restrict__ slabs) {      // [4][(T+1)][H] bf16
  __shared__ __align__(16) bf16 As[2][128 * 64];  // 32 KB
  __shared__ __align__(16) bf16 Bs[2][64 * 64];   // 16 KB
  const int e = blockIdx.y, z = blockIdx.z;
  const int ntiles = cntpad[e] >> 7;
  const int n0 = blockIdx.x * 64;
  const int ebase = e * CAP;
  const int tid = threadIdx.x, lane = tid & 63, wid = tid >> 6;
  const int wm = (wid >> 1) * 64, wh = (wid & 1) * 32;
  const int lcol = lane & 15, lquad = lane >> 4;
  const int l7 = lcol & 7;
  const int srow = tid >> 3;
  const int swz = ((tid & 7) ^ (srow & 7)) * 8;
  const int r = tid >> 2;
  const int c0 = (tid & 3) * 4;
  const float* gB = down + (size_t)e * HDIM * IDIM + (size_t)(n0 + r) * IDIM + c0;
  int wb[4];
#pragma unroll
  for (int j = 0; j < 4; ++j) {
    int c = c0 + 16 * j;
    wb[j] = (((c >> 3) ^ (r & 7)) * 8) + (c & 7);
  }
  const int bst = r * 64;

  for (int mt = z; mt < ntiles; mt += 3) {
    const size_t rbase = (size_t)(ebase + mt * 128);
    const bf16* gA[4];
#pragma unroll
    for (int q = 0; q < 4; ++q)
      gA[q] = hsc + (rbase + srow + 32 * q) * IDIM + swz;
    f32x4 acc[4][2];
#pragma unroll
    for (int mf = 0; mf < 4; ++mf) {
      acc[mf][0] = f32x4{0.f, 0.f, 0.f, 0.f};
      acc[mf][1] = f32x4{0.f, 0.f, 0.f, 0.f};
    }
    float4 bvA[4], bvB[4];
    // prologue: B(0), A(0), B(1)
#pragma unroll
    for (int j = 0; j < 4; ++j) bvA[j] = *(const float4*)(gB + 16 * j);
    SB();
#pragma unroll
    for (int q = 0; q < 4; ++q)
      lds_load16(&As[0][tid * 8 + q * 2048], gA[q]);
    SB();
#pragma unroll
    for (int j = 0; j < 4; ++j) bvB[j] = *(const float4*)(gB + 64 + 16 * j);
    SB();

    auto STEP = [&](int k, int cur, float4 (&bcur)[4]) {
      const int nxt = cur ^ 1;
      if (k == 7) { WAIT_VM0; } else { WAIT_VM4; }
      SB();
#pragma unroll
      for (int j = 0; j < 4; ++j)
        *(bf16x4*)&Bs[cur][bst + wb[j]] = cvt4(bcur[j]);
      LGKM0();
      SB();
      BAR();
      SB();
      if (k + 1 < 8) {
#pragma unroll
        for (int q = 0; q < 4; ++q)
          lds_load16(&As[nxt][tid * 8 + q * 2048], gA[q] + (k + 1) * 64);
      }
      SB();
      if (k + 2 < 8) {
#pragma unroll
        for (int j = 0; j < 4; ++j)
          bcur[j] = *(const float4*)(gB + (k + 2) * 64 + 16 * j);
      }
      SB();
#pragma unroll
      for (int ks = 0; ks < 2; ++ks) {
        const int sw = ((ks * 4 + lquad) ^ l7) * 8;
        bf16x8 b0 = *(const bf16x8*)&Bs[cur][(wh + lcol) * 64 + sw];
        bf16x8 b1 = *(const bf16x8*)&Bs[cur][(wh + 16 + lcol) * 64 + sw];
#pragma unroll
        for (int mf = 0; mf < 4; ++mf) {
          bf16x8 af = *(const bf16x8*)&As[cur][(wm + mf * 16 + lcol) * 64 + sw];
          acc[mf][0] = __builtin_amdgcn_mfma_f32_16x16x32_bf16(af, b0, acc[mf][0], 0, 0, 0);
          acc[mf][1] = __builtin_amdgcn_mfma_f32_16x16x32_bf16(af, b1, acc[mf][1], 0, 0, 0);
        }
      }
    };
#pragma unroll
    for (int kk = 0; kk < 4; ++kk) {   // IDIM/64 = 8 steps
      STEP(2 * kk,     0, bvA);
      STEP(2 * kk + 1, 1, bvB);
    }
    // epilogue: bf16 scatter stores (each (t,k) slab row written once per n-slice)
#pragma unroll
    for (int mf = 0; mf < 4; ++mf) {
#pragma unroll
      for (int rr = 0; rr < 4; ++rr) {
        const int tk = etk[ebase + mt * 128 + wm + mf * 16 + lquad * 4 + rr];
        const int tok = tk >> 2, kslot = tk & 3;
        bf16* orow = slabs + ((size_t)kslot * (T_TOK + 1) + tok) * HDIM + n0 + wh + lcol;
        orow[0]  = (bf16)acc[mf][0][rr];
        orow[16] = (bf16)acc[mf][1][rr];
      }
    }
  }
}

// ---------------- reduce: out = sum of 4 bf16 slabs (8 elems/thread) ----------------

__global__ void reduce_kernel(const bf16* __restrict__ slabs, float* __restrict__ out) {
  const size_t stride8 = (size_t)(T_TOK + 1) * HDIM / 8;   // in bf16x8 units
  int i = blockIdx.x * blockDim.x + threadIdx.x;           // 8-elem group index
  bf16x8 a = ((const bf16x8*)slabs)[i];
  bf16x8 b = ((const bf16x8*)slabs)[i + stride8];
  bf16x8 c = ((const bf16x8*)slabs)[i + 2 * stride8];
  bf16x8 d = ((const bf16x8*)slabs)[i + 3 * stride8];
  float4 o0, o1;
  float r[8];
#pragma unroll
  for (int j = 0; j < 8; ++j)
    r[j] = (float)a[j] + (float)b[j] + (float)c[j] + (float)d[j];
  o0.x = r[0]; o0.y = r[1]; o0.z = r[2]; o0.w = r[3];
  o1.x = r[4]; o1.y = r[5]; o1.z = r[6]; o1.w = r[7];
  ((float4*)out)[i * 2]     = o0;
  ((float4*)out)[i * 2 + 1] = o1;
}

// ---------------- launch ----------------

extern "C" void kernel_launch(void* const* d_in, const int* in_sizes, int n_in,
                              void* d_out, int out_size, void* d_ws, size_t ws_size,
                              hipStream_t stream) {
  const float* hid_f  = (const float*)d_in[0];
  const int*   idx    = (const int*)d_in[1];
  const float* tw     = (const float*)d_in[2];
  const float* gup_f  = (const float*)d_in[3];
  const float* down_f = (const float*)d_in[4];
  float* out = (float*)d_out;

  uint8_t* ws = (uint8_t*)d_ws;
  size_t off = 0;
  bf16* hid_b = (bf16*)(ws + off);   off += (size_t)(T_TOK + 1) * HDIM * 2;
  int*  etk   = (int*)(ws + off);    off += (size_t)NEXP * CAP * 4;
  float* ewt  = (float*)(ws + off);  off += (size_t)NEXP * CAP * 4;
  int* cntpad = (int*)(ws + off);    off += 256;
  bf16* hsc   = (bf16*)(ws + off);   off += (size_t)NEXP * CAP * IDIM * 2;
  bf16* slabs = (bf16*)(ws + off);   // 4*(T+1)*H*2 ≈ 8.4 MB

  prep_kernel<<<dim3(CVT_BLOCKS + NEXP), dim3(256), 0, stream>>>(
      hid_f, hid_b, idx, tw, etk, ewt, cntpad);
  gemm1_kernel<<<dim3(IDIM / 32, NEXP, 3), dim3(256), 0, stream>>>(
      hid_b, gup_f, etk, ewt, cntpad, hsc);
  gemm2_kernel<<<dim3(HDIM / 64, NEXP, 3), dim3(256), 0, stream>>>(
      hsc, down_f, etk, cntpad, slabs);
  reduce_kernel<<<dim3(T_TOK * HDIM / 8 / 256), dim3(256), 0, stream>>>(slabs, out);
}